// Round 4
// baseline (285.009 us; speedup 1.0000x reference)
//
#include <hip/hip_runtime.h>

// B=2, L=16384, Nv=8, C=196, H=4, d=49.
// Factored algorithm (per position t):
//   qln = LN(query);  qk[h,c] = sum_d qln[h*49+d]*Wk[h*49+d,c]          (GEMM1, MFMA)
//   score[h,n] = (sum_c qk[h,c]*ctx[n,c] + qln_h.bk_h)/7 ; p = softmax  (VALU)
//   cbar[h,c] = sum_n p[h,n]*ctx[n,c]                                   (VALU)
//   out[o] = sum_c cbar[h(o),c]*Wv[o,c] + bv[o]                         (GEMM2, MFMA)
// Weights are packed ONCE (pack_panels -> d_ws) into fragment-native bf16
// panels; the main kernel feeds MFMA B-operands straight from L2.
namespace {
constexpr int kL = 16384;
constexpr int kTile = 16;              // positions per WG
constexpr float kEps = 1e-5f;
constexpr float kScale = 1.0f / 7.0f;  // 1/sqrt(49)

typedef short bf16x8 __attribute__((ext_vector_type(8)));  // 8 bf16 (4 VGPR)
typedef float f32x4 __attribute__((ext_vector_type(4)));

__device__ __forceinline__ unsigned short f2bf(float x) {  // RNE f32->bf16
  unsigned u = __builtin_bit_cast(unsigned, x);
  u = u + 0x7fffu + ((u >> 16) & 1u);
  return (unsigned short)(u >> 16);
}
__device__ __forceinline__ float bf2f(unsigned short s) {
  return __builtin_bit_cast(float, (unsigned)s << 16);
}

// LDS geometry (bf16 elements)
constexpr int QLN_ROW = 296;   // 4 h-blocks of 72 (d 49..63 zero-padded)
constexpr int QK_ROW  = 904;   // 4 h-blocks of 224 (c 196..223 zero-padded)

// Global panel geometry (fragment-native: slot = blk*512 + lane*8 + i)
constexpr int PK_ELEMS = 4 * 13 * 2 * 512;  // h, nt(c-tiles), ks(k=64)   = 53248
constexpr int PV_ELEMS = 4 * 4 * 7 * 512;   // h, nt(o-tiles), ks(k=224)  = 57344
constexpr size_t PANEL_BYTES = (size_t)(PK_ELEMS + PV_ELEMS) * sizeof(unsigned short);

// ======================= panel pack (runs once, tiny) =======================
__global__ void pack_panels(const float* __restrict__ Wk, const float* __restrict__ Wv,
                            unsigned short* __restrict__ pK, unsigned short* __restrict__ pV)
{
  int gid = blockIdx.x * 256 + threadIdx.x;
  if (gid < PK_ELEMS / 8) {
    int blk = gid >> 6;          // (h*13+nt)*2+ks
    int lane = gid & 63;
    int ks = blk & 1;
    int hnt = blk >> 1;
    int h = hnt / 13, nt = hnt % 13;
    int c = nt * 16 + (lane & 15);
    int d0 = ks * 32 + (lane >> 4) * 8;
    unsigned short v[8];
    #pragma unroll
    for (int i = 0; i < 8; ++i) {
      int d = d0 + i;
      float w = (d < 49 && c < 196) ? Wk[(size_t)(h * 49 + d) * 196 + c] : 0.f;
      v[i] = f2bf(w);
    }
    *reinterpret_cast<int4*>(&pK[(size_t)gid * 8]) = *reinterpret_cast<const int4*>(v);
  } else if (gid < PK_ELEMS / 8 + PV_ELEMS / 8) {
    int g2 = gid - PK_ELEMS / 8;
    int blk = g2 >> 6;           // (h*4+nt)*7+ks
    int lane = g2 & 63;
    int ks = blk % 7;
    int hnt = blk / 7;
    int h = hnt >> 2, nt = hnt & 3;
    int o = nt * 16 + (lane & 15);
    int c0 = ks * 32 + (lane >> 4) * 8;
    unsigned short v[8];
    #pragma unroll
    for (int i = 0; i < 8; ++i) {
      int c = c0 + i;
      float w = (o < 49 && c < 196) ? Wv[(size_t)(h * 49 + o) * 196 + c] : 0.f;
      v[i] = f2bf(w);
    }
    *reinterpret_cast<int4*>(&pV[(size_t)g2 * 8]) = *reinterpret_cast<const int4*>(v);
  }
}

// =============================== main kernel ================================
__global__ __launch_bounds__(256, 4)
void fused_main(const float* __restrict__ query, const float* __restrict__ context,
                const unsigned short* __restrict__ pK, const float* __restrict__ bk,
                const unsigned short* __restrict__ pV, const float* __restrict__ bv,
                const float* __restrict__ gamma, const float* __restrict__ beta,
                float* __restrict__ out, float* __restrict__ attn)
{
  __shared__ __align__(16) unsigned short qlnS[16 * QLN_ROW];  // 9472 B
  __shared__ __align__(16) unsigned short qkcb[16 * QK_ROW];   // 28928 B (qk, then cbar)
  __shared__ float sred[16 * 4 * 8];                           // 2048 B (scores -> probs)

  const int tid = threadIdx.x;
  const int pos0 = blockIdx.x * kTile;
  const int lane = tid & 63;
  const int wv = tid >> 6;      // wave 0..3
  const int l15 = lane & 15;
  const int g = lane >> 4;

  const float4* ctxF4 = reinterpret_cast<const float4*>(context);

  // ---------------- A: LayerNorm -> qln bf16 (h-blocked, k-padded) ------------
  {
    const int r = tid >> 4, s = tid & 15;
    const float4* q4 = reinterpret_cast<const float4*>(query) + (size_t)(pos0 + r) * 49;
    const float4* g4 = reinterpret_cast<const float4*>(gamma);
    const float4* b4 = reinterpret_cast<const float4*>(beta);
    float4 xv[4];
    float sum = 0.f, sumsq = 0.f;
    #pragma unroll
    for (int k = 0; k < 4; ++k) {
      int i4 = s + 16 * k;
      if (i4 < 49) {
        xv[k] = q4[i4];
        sum += xv[k].x + xv[k].y + xv[k].z + xv[k].w;
        sumsq += xv[k].x*xv[k].x + xv[k].y*xv[k].y + xv[k].z*xv[k].z + xv[k].w*xv[k].w;
      }
    }
    #pragma unroll
    for (int m = 1; m < 16; m <<= 1) {
      sum += __shfl_xor(sum, m, 16);
      sumsq += __shfl_xor(sumsq, m, 16);
    }
    const float mu = sum * (1.0f / 196.0f);
    const float var = sumsq * (1.0f / 196.0f) - mu * mu;
    const float rstd = rsqrtf(var + kEps);
    #pragma unroll
    for (int k = 0; k < 4; ++k) {
      int i4 = s + 16 * k;
      if (i4 < 49) {
        float4 gv = g4[i4], bt = b4[i4];
        float vo[4];
        vo[0] = (xv[k].x - mu) * rstd * gv.x + bt.x;
        vo[1] = (xv[k].y - mu) * rstd * gv.y + bt.y;
        vo[2] = (xv[k].z - mu) * rstd * gv.z + bt.z;
        vo[3] = (xv[k].w - mu) * rstd * gv.w + bt.w;
        #pragma unroll
        for (int j = 0; j < 4; ++j) {
          int oo = 4 * i4 + j;
          int hq = oo / 49, dq = oo - 49 * hq;
          qlnS[r * QLN_ROW + hq * 72 + dq] = f2bf(vo[j]);
        }
      }
    }
    #pragma unroll
    for (int it = 0; it < 6; ++it) {   // zero d-pad 49..71 per h-block
      int pp = s + 16 * it;
      if (pp < 92) {
        int hz = pp / 23, dz = 49 + pp - 23 * hz;
        qlnS[r * QLN_ROW + hz * 72 + dz] = 0;
      }
    }
  }
  __syncthreads();

  // ---------------- B: GEMM1 (52 (h,nt) tiles over 4 waves, no barriers) ------
  {
    #pragma unroll 1
    for (int j = 0; j < 13; ++j) {
      int idx = wv + 4 * j;          // 0..51
      int h = idx / 13, nt = idx - 13 * h;
      bf16x8 a0 = *reinterpret_cast<const bf16x8*>(&qlnS[l15 * QLN_ROW + h * 72 + g * 8]);
      bf16x8 a1 = *reinterpret_cast<const bf16x8*>(&qlnS[l15 * QLN_ROW + h * 72 + 32 + g * 8]);
      const unsigned short* pb = pK + ((size_t)(h * 13 + nt) * 2) * 512 + lane * 8;
      f32x4 acc = {0.f, 0.f, 0.f, 0.f};
      bf16x8 b0 = *reinterpret_cast<const bf16x8*>(pb);
      acc = __builtin_amdgcn_mfma_f32_16x16x32_bf16(a0, b0, acc, 0, 0, 0);
      bf16x8 b1 = *reinterpret_cast<const bf16x8*>(pb + 512);
      acc = __builtin_amdgcn_mfma_f32_16x16x32_bf16(a1, b1, acc, 0, 0, 0);
      #pragma unroll
      for (int r = 0; r < 4; ++r)      // D[row=g*4+r][col=nt*16+l15]
        qkcb[(g * 4 + r) * QK_ROW + h * 224 + nt * 16 + l15] = f2bf(acc[r]);
    }
  }
  __syncthreads();

  // ---------------- C: scores (ctx read #1) + softmax -------------------------
  const int t = tid >> 4;
  const int x = tid & 15;
  const size_t ctxBase = (size_t)(pos0 + t) * (8 * 49);
  {
    float s[4][8];
    #pragma unroll
    for (int hh = 0; hh < 4; ++hh)
      #pragma unroll
      for (int n = 0; n < 8; ++n) s[hh][n] = 0.f;
    #pragma unroll
    for (int jj = 0; jj < 4; ++jj) {
      int c4 = x + 16 * jj;
      if (c4 < 49) {
        float qv[4][4];
        #pragma unroll
        for (int hh = 0; hh < 4; ++hh) {
          int2 q = *reinterpret_cast<const int2*>(&qkcb[t * QK_ROW + hh * 224 + 4 * c4]);
          qv[hh][0] = __builtin_bit_cast(float, (unsigned)q.x << 16);
          qv[hh][1] = __builtin_bit_cast(float, (unsigned)q.x & 0xffff0000u);
          qv[hh][2] = __builtin_bit_cast(float, (unsigned)q.y << 16);
          qv[hh][3] = __builtin_bit_cast(float, (unsigned)q.y & 0xffff0000u);
        }
        #pragma unroll
        for (int n = 0; n < 8; ++n) {
          float4 cv = ctxF4[ctxBase + n * 49 + c4];
          #pragma unroll
          for (int hh = 0; hh < 4; ++hh)
            s[hh][n] += qv[hh][0]*cv.x + qv[hh][1]*cv.y + qv[hh][2]*cv.z + qv[hh][3]*cv.w;
        }
      }
    }
    #pragma unroll
    for (int hh = 0; hh < 4; ++hh)
      #pragma unroll
      for (int n = 0; n < 8; ++n) {
        float v = s[hh][n];
        #pragma unroll
        for (int m = 1; m < 16; m <<= 1) v += __shfl_xor(v, m, 16);
        if (x == 0) sred[(t * 4 + hh) * 8 + n] = v;
      }
  }
  __syncthreads();
  if (tid < 64) {
    const int tt = tid & 15, hh = tid >> 4;
    float qb = 0.f;
    for (int d = 0; d < 49; ++d)
      qb += bf2f(qlnS[tt * QLN_ROW + hh * 72 + d]) * bk[hh * 49 + d];
    const int pos = pos0 + tt;
    const int bb = pos >> 14, ll = pos & (kL - 1);
    float sc[8], m = -1e30f;
    #pragma unroll
    for (int n = 0; n < 8; ++n) {
      sc[n] = (sred[(tt * 4 + hh) * 8 + n] + qb) * kScale;
      m = fmaxf(m, sc[n]);
    }
    float ssum = 0.f;
    #pragma unroll
    for (int n = 0; n < 8; ++n) { sc[n] = __expf(sc[n] - m); ssum += sc[n]; }
    const float inv = 1.0f / ssum;
    float* ap = attn + (((size_t)bb * 4 + hh) * kL + ll) * 8;
    #pragma unroll
    for (int n = 0; n < 8; ++n) {
      float p = sc[n] * inv;
      sred[(tt * 4 + hh) * 8 + n] = p;   // scores -> probs in place
      ap[n] = p;
    }
  }
  __syncthreads();

  // ---------------- D: cbar (ctx read #2, L2-hot) -> bf16 into qkcb -----------
  {
    float preg[4][8];
    #pragma unroll
    for (int hh = 0; hh < 4; ++hh)
      #pragma unroll
      for (int n = 0; n < 8; ++n) preg[hh][n] = sred[(t * 4 + hh) * 8 + n];
    #pragma unroll 1
    for (int jj = 0; jj < 4; ++jj) {
      int c4 = x + 16 * jj;
      if (c4 < 49) {
        float acc[4][4];
        #pragma unroll
        for (int hh = 0; hh < 4; ++hh)
          #pragma unroll
          for (int e = 0; e < 4; ++e) acc[hh][e] = 0.f;
        #pragma unroll
        for (int n = 0; n < 8; ++n) {
          float4 cv = ctxF4[ctxBase + n * 49 + c4];
          #pragma unroll
          for (int hh = 0; hh < 4; ++hh) {
            float p = preg[hh][n];
            acc[hh][0] += p * cv.x; acc[hh][1] += p * cv.y;
            acc[hh][2] += p * cv.z; acc[hh][3] += p * cv.w;
          }
        }
        #pragma unroll
        for (int hh = 0; hh < 4; ++hh) {
          ushort4 pk4;
          pk4.x = f2bf(acc[hh][0]); pk4.y = f2bf(acc[hh][1]);
          pk4.z = f2bf(acc[hh][2]); pk4.w = f2bf(acc[hh][3]);
          *reinterpret_cast<ushort4*>(&qkcb[t * QK_ROW + hh * 224 + 4 * c4]) = pk4;
        }
      }
    }
    #pragma unroll
    for (int it = 0; it < 2; ++it) {   // zero c-pad 196..223
      int ii = tid + 256 * it;
      if (ii < 448) {
        int tz = ii / 28, rem = ii - 28 * tz;
        int hz = rem / 7, c4p = 49 + rem - 7 * hz;
        ushort4 z = {0, 0, 0, 0};
        *reinterpret_cast<ushort4*>(&qkcb[tz * QK_ROW + hz * 224 + 4 * c4p]) = z;
      }
    }
  }
  __syncthreads();

  // ---------------- E: GEMM2 (wave wv = head wv; 4 o-tiles) -------------------
  {
    const int h = wv;
    bf16x8 a[7];
    #pragma unroll
    for (int ks = 0; ks < 7; ++ks)
      a[ks] = *reinterpret_cast<const bf16x8*>(&qkcb[l15 * QK_ROW + h * 224 + ks * 32 + g * 8]);
    #pragma unroll 1
    for (int nt = 0; nt < 4; ++nt) {
      const unsigned short* pb = pV + ((size_t)(h * 4 + nt) * 7) * 512 + lane * 8;
      f32x4 acc = {0.f, 0.f, 0.f, 0.f};
      #pragma unroll
      for (int ks = 0; ks < 7; ++ks) {
        bf16x8 b = *reinterpret_cast<const bf16x8*>(pb + (size_t)ks * 512);
        acc = __builtin_amdgcn_mfma_f32_16x16x32_bf16(a[ks], b, acc, 0, 0, 0);
      }
      int o = nt * 16 + l15;
      if (o < 49) {
        float bvv = bv[h * 49 + o];
        #pragma unroll
        for (int r = 0; r < 4; ++r)
          out[(size_t)(pos0 + g * 4 + r) * 196 + h * 49 + o] = acc[r] + bvv;
      }
    }
  }
}

// ===================== fallback (round-3 kernel, ws-free) =====================
constexpr int PNL_ELEMS = 14336;

__global__ __launch_bounds__(256, 2)
void fused_triplane_v3(const float* __restrict__ query,
                    const float* __restrict__ context,
                    const float* __restrict__ Wk, const float* __restrict__ bk,
                    const float* __restrict__ Wv, const float* __restrict__ bv,
                    const float* __restrict__ gamma, const float* __restrict__ beta,
                    float* __restrict__ out, float* __restrict__ attn)
{
  __shared__ __align__(16) unsigned short pnl[PNL_ELEMS];
  __shared__ __align__(16) unsigned short qlnS[16 * QLN_ROW];
  __shared__ __align__(16) unsigned short qkcb[16 * QK_ROW];
  __shared__ float sred[16 * 4 * 8];

  const int tid = threadIdx.x;
  const int pos0 = blockIdx.x * kTile;
  const int lane = tid & 63;
  const int wv = tid >> 6;
  const int l15 = lane & 15;
  const int g = lane >> 4;

  const float4* WkF4 = reinterpret_cast<const float4*>(Wk);
  const float4* WvF4 = reinterpret_cast<const float4*>(Wv);
  const float4* ctxF4 = reinterpret_cast<const float4*>(context);

  {
    const int r = tid >> 4, s = tid & 15;
    const float4* q4 = reinterpret_cast<const float4*>(query) + (size_t)(pos0 + r) * 49;
    const float4* g4 = reinterpret_cast<const float4*>(gamma);
    const float4* b4 = reinterpret_cast<const float4*>(beta);
    float4 xv[4];
    float sum = 0.f, sumsq = 0.f;
    #pragma unroll
    for (int k = 0; k < 4; ++k) {
      int i4 = s + 16 * k;
      if (i4 < 49) {
        xv[k] = q4[i4];
        sum += xv[k].x + xv[k].y + xv[k].z + xv[k].w;
        sumsq += xv[k].x*xv[k].x + xv[k].y*xv[k].y + xv[k].z*xv[k].z + xv[k].w*xv[k].w;
      }
    }
    #pragma unroll
    for (int m = 1; m < 16; m <<= 1) {
      sum += __shfl_xor(sum, m, 16);
      sumsq += __shfl_xor(sumsq, m, 16);
    }
    const float mu = sum * (1.0f / 196.0f);
    const float var = sumsq * (1.0f / 196.0f) - mu * mu;
    const float rstd = rsqrtf(var + kEps);
    #pragma unroll
    for (int k = 0; k < 4; ++k) {
      int i4 = s + 16 * k;
      if (i4 < 49) {
        float4 gv = g4[i4], bt = b4[i4];
        float vo[4];
        vo[0] = (xv[k].x - mu) * rstd * gv.x + bt.x;
        vo[1] = (xv[k].y - mu) * rstd * gv.y + bt.y;
        vo[2] = (xv[k].z - mu) * rstd * gv.z + bt.z;
        vo[3] = (xv[k].w - mu) * rstd * gv.w + bt.w;
        #pragma unroll
        for (int j = 0; j < 4; ++j) {
          int oo = 4 * i4 + j;
          int hq = oo / 49, dq = oo - 49 * hq;
          qlnS[r * QLN_ROW + hq * 72 + dq] = f2bf(vo[j]);
        }
      }
    }
    #pragma unroll
    for (int it = 0; it < 6; ++it) {
      int pp = s + 16 * it;
      if (pp < 92) {
        int hz = pp / 23, dz = 49 + pp - 23 * hz;
        qlnS[r * QLN_ROW + hz * 72 + dz] = 0;
      }
    }
    #pragma unroll
    for (int k = 0; k < 7; ++k) {
      int idx8 = tid + 256 * k;
      *reinterpret_cast<int4*>(&pnl[idx8 * 8]) = make_int4(0, 0, 0, 0);
    }
  }
  __syncthreads();

  for (int h = 0; h < 4; ++h) {
    for (int it = 0; it < 10; ++it) {
      int idx = tid + 256 * it;
      if (idx < 2401) {
        int d = idx / 49, c4 = idx - 49 * d;
        float4 w = WkF4[(size_t)(h * 49 + d) * 49 + c4];
        int ks = d >> 5, gg = (d & 31) >> 3, ii = d & 7;
        float wa[4] = {w.x, w.y, w.z, w.w};
        #pragma unroll
        for (int j = 0; j < 4; ++j) {
          int cc = 4 * c4 + j;
          int nt = cc >> 4, lc = cc & 15;
          pnl[((nt << 1) | ks) * 512 + (gg * 16 + lc) * 8 + ii] = f2bf(wa[j]);
        }
      }
    }
    __syncthreads();
    {
      const bf16x8 a0 = *reinterpret_cast<const bf16x8*>(&qlnS[l15 * QLN_ROW + h * 72 + g * 8]);
      const bf16x8 a1 = *reinterpret_cast<const bf16x8*>(&qlnS[l15 * QLN_ROW + h * 72 + 32 + g * 8]);
      for (int nt = wv; nt < 13; nt += 4) {
        f32x4 acc = {0.f, 0.f, 0.f, 0.f};
        bf16x8 b0 = *reinterpret_cast<const bf16x8*>(&pnl[(nt * 2 + 0) * 512 + lane * 8]);
        acc = __builtin_amdgcn_mfma_f32_16x16x32_bf16(a0, b0, acc, 0, 0, 0);
        bf16x8 b1 = *reinterpret_cast<const bf16x8*>(&pnl[(nt * 2 + 1) * 512 + lane * 8]);
        acc = __builtin_amdgcn_mfma_f32_16x16x32_bf16(a1, b1, acc, 0, 0, 0);
        #pragma unroll
        for (int r = 0; r < 4; ++r)
          qkcb[(g * 4 + r) * QK_ROW + h * 224 + nt * 16 + l15] = f2bf(acc[r]);
      }
    }
    __syncthreads();
  }

  const int t = tid >> 4;
  const int x = tid & 15;
  for (int n = 0; n < 8; ++n) {
    float sph[4] = {0.f, 0.f, 0.f, 0.f};
    #pragma unroll
    for (int jj = 0; jj < 4; ++jj) {
      int c4 = x + 16 * jj;
      if (c4 < 49) {
        float4 cv = ctxF4[((size_t)(pos0 + t) * 8 + n) * 49 + c4];
        #pragma unroll
        for (int hh = 0; hh < 4; ++hh) {
          int2 q = *reinterpret_cast<const int2*>(&qkcb[t * QK_ROW + hh * 224 + 4 * c4]);
          float q0 = __builtin_bit_cast(float, (unsigned)q.x << 16);
          float q1 = __builtin_bit_cast(float, (unsigned)q.x & 0xffff0000u);
          float q2 = __builtin_bit_cast(float, (unsigned)q.y << 16);
          float q3 = __builtin_bit_cast(float, (unsigned)q.y & 0xffff0000u);
          sph[hh] += q0 * cv.x + q1 * cv.y + q2 * cv.z + q3 * cv.w;
        }
      }
    }
    #pragma unroll
    for (int hh = 0; hh < 4; ++hh) {
      #pragma unroll
      for (int m = 1; m < 16; m <<= 1) sph[hh] += __shfl_xor(sph[hh], m, 16);
    }
    if (x == 0) {
      #pragma unroll
      for (int hh = 0; hh < 4; ++hh) sred[(t * 4 + hh) * 8 + n] = sph[hh];
    }
  }
  __syncthreads();
  if (tid < 64) {
    const int tt = tid & 15, hh = tid >> 4;
    float qb = 0.f;
    for (int d = 0; d < 49; ++d)
      qb += bf2f(qlnS[tt * QLN_ROW + hh * 72 + d]) * bk[hh * 49 + d];
    const int pos = pos0 + tt;
    const int bb = pos >> 14, ll = pos & (kL - 1);
    float sc[8], m = -1e30f;
    #pragma unroll
    for (int n = 0; n < 8; ++n) {
      sc[n] = (sred[(tt * 4 + hh) * 8 + n] + qb) * kScale;
      m = fmaxf(m, sc[n]);
    }
    float ssum = 0.f;
    #pragma unroll
    for (int n = 0; n < 8; ++n) { sc[n] = __expf(sc[n] - m); ssum += sc[n]; }
    const float inv = 1.0f / ssum;
    float* ap = attn + (((size_t)bb * 4 + hh) * kL + ll) * 8;
    #pragma unroll
    for (int n = 0; n < 8; ++n) {
      float p = sc[n] * inv;
      sred[(tt * 4 + hh) * 8 + n] = p;
      ap[n] = p;
    }
  }
  __syncthreads();

  {
    float preg[4][8];
    #pragma unroll
    for (int hh = 0; hh < 4; ++hh)
      #pragma unroll
      for (int n = 0; n < 8; ++n) preg[hh][n] = sred[(t * 4 + hh) * 8 + n];
    #pragma unroll 1
    for (int jj = 0; jj < 4; ++jj) {
      int c4 = x + 16 * jj;
      if (c4 < 49) {
        float acc[4][4];
        #pragma unroll
        for (int hh = 0; hh < 4; ++hh)
          #pragma unroll
          for (int e = 0; e < 4; ++e) acc[hh][e] = 0.f;
        #pragma unroll
        for (int n = 0; n < 8; ++n) {
          float4 cv = ctxF4[((size_t)(pos0 + t) * 8 + n) * 49 + c4];
          #pragma unroll
          for (int hh = 0; hh < 4; ++hh) {
            float p = preg[hh][n];
            acc[hh][0] += p * cv.x; acc[hh][1] += p * cv.y;
            acc[hh][2] += p * cv.z; acc[hh][3] += p * cv.w;
          }
        }
        #pragma unroll
        for (int hh = 0; hh < 4; ++hh) {
          ushort4 pk4;
          pk4.x = f2bf(acc[hh][0]); pk4.y = f2bf(acc[hh][1]);
          pk4.z = f2bf(acc[hh][2]); pk4.w = f2bf(acc[hh][3]);
          *reinterpret_cast<ushort4*>(&qkcb[t * QK_ROW + hh * 224 + 4 * c4]) = pk4;
        }
      }
    }
    #pragma unroll
    for (int it = 0; it < 2; ++it) {
      int ii = tid + 256 * it;
      if (ii < 448) {
        int tz = ii / 28, rem = ii - 28 * tz;
        int hz = rem / 7, c4p = 49 + rem - 7 * hz;
        ushort4 z = {0, 0, 0, 0};
        *reinterpret_cast<ushort4*>(&qkcb[tz * QK_ROW + hz * 224 + 4 * c4p]) = z;
      }
    }
    #pragma unroll
    for (int k = 0; k < 7; ++k) {
      int idx8 = tid + 256 * k;
      *reinterpret_cast<int4*>(&pnl[idx8 * 8]) = make_int4(0, 0, 0, 0);
    }
  }
  __syncthreads();

  for (int h = 0; h < 4; ++h) {
    for (int it = 0; it < 10; ++it) {
      int idx = tid + 256 * it;
      if (idx < 2401) {
        int o = idx / 49, c4 = idx - 49 * o;
        float4 w = WvF4[(size_t)(h * 49 + o) * 49 + c4];
        int c0 = 4 * c4;
        int nt = o >> 4, lo = o & 15;
        int ks = c0 >> 5, gg = (c0 & 31) >> 3, i0 = c0 & 7;
        ushort4 pk4;
        pk4.x = f2bf(w.x); pk4.y = f2bf(w.y); pk4.z = f2bf(w.z); pk4.w = f2bf(w.w);
        *reinterpret_cast<ushort4*>(&pnl[(nt * 7 + ks) * 512 + (gg * 16 + lo) * 8 + i0]) = pk4;
      }
    }
    __syncthreads();
    {
      f32x4 acc = {0.f, 0.f, 0.f, 0.f};
      #pragma unroll
      for (int ks = 0; ks < 7; ++ks) {
        bf16x8 a = *reinterpret_cast<const bf16x8*>(&qkcb[l15 * QK_ROW + h * 224 + ks * 32 + g * 8]);
        bf16x8 b = *reinterpret_cast<const bf16x8*>(&pnl[(wv * 7 + ks) * 512 + lane * 8]);
        acc = __builtin_amdgcn_mfma_f32_16x16x32_bf16(a, b, acc, 0, 0, 0);
      }
      int o = wv * 16 + l15;
      if (o < 49) {
        float bvv = bv[h * 49 + o];
        #pragma unroll
        for (int r = 0; r < 4; ++r) {
          int tt2 = g * 4 + r;
          out[(size_t)(pos0 + tt2) * 196 + h * 49 + o] = acc[r] + bvv;
        }
      }
    }
    __syncthreads();
  }
}
} // namespace

extern "C" void kernel_launch(void* const* d_in, const int* in_sizes, int n_in,
                              void* d_out, int out_size, void* d_ws, size_t ws_size,
                              hipStream_t stream) {
  const float* query   = (const float*)d_in[0];
  const float* context = (const float*)d_in[1];
  const float* Wk      = (const float*)d_in[2];
  const float* bk      = (const float*)d_in[3];
  const float* Wv      = (const float*)d_in[4];
  const float* bv      = (const float*)d_in[5];
  const float* gamma   = (const float*)d_in[6];
  const float* beta    = (const float*)d_in[7];
  float* outp = (float*)d_out;
  float* attn = outp + (size_t)2 * kL * 196;   // out [B,L,C] then attn [B,H,L,Nv]

  const int nwg = (2 * kL) / kTile;  // 2048
  if (ws_size >= PANEL_BYTES) {
    unsigned short* pK = (unsigned short*)d_ws;
    unsigned short* pV = pK + PK_ELEMS;
    const int packThreads = (PK_ELEMS + PV_ELEMS) / 8;           // 13824
    pack_panels<<<dim3((packThreads + 255) / 256), dim3(256), 0, stream>>>(Wk, Wv, pK, pV);
    fused_main<<<dim3(nwg), dim3(256), 0, stream>>>(
        query, context, pK, bk, pV, bv, gamma, beta, outp, attn);
  } else {
    fused_triplane_v3<<<dim3(nwg), dim3(256), 0, stream>>>(
        query, context, Wk, bk, Wv, bv, gamma, beta, outp, attn);
  }
}

// Round 5
// 107.727 us; speedup vs baseline: 2.6457x; 2.6457x over previous
//
#include <hip/hip_runtime.h>

// B=2, L=16384, Nv=8, C=196, H=4, d=49.
// Factored algorithm (per position t):
//   qln = LN(query);  qk[h,c] = sum_d qln[h*49+d]*Wk[h*49+d,c]          (GEMM1, MFMA)
//   score[h,n] = (sum_c qk[h,c]*ctx[n,c] + qln_h.bk_h)/7 ; p = softmax  (VALU)
//   cbar[h,c] = sum_n p[h,n]*ctx[n,c]                                   (VALU)
//   out[o] = sum_c cbar[h(o),c]*Wv[o,c] + bv[o]                         (GEMM2, MFMA)
// Weights packed ONCE (pack_panels -> d_ws) into fragment-native bf16 panels;
// main kernel feeds MFMA B-operands straight from L2. Phases A/C/D use the
// round-3 low-live-state structure (proven spill-free, VGPR 112).
namespace {
constexpr int kL = 16384;
constexpr int kTile = 16;              // positions per WG
constexpr float kEps = 1e-5f;
constexpr float kScale = 1.0f / 7.0f;  // 1/sqrt(49)

typedef short bf16x8 __attribute__((ext_vector_type(8)));  // 8 bf16 (4 VGPR)
typedef float f32x4 __attribute__((ext_vector_type(4)));

__device__ __forceinline__ unsigned short f2bf(float x) {  // RNE f32->bf16
  unsigned u = __builtin_bit_cast(unsigned, x);
  u = u + 0x7fffu + ((u >> 16) & 1u);
  return (unsigned short)(u >> 16);
}
__device__ __forceinline__ float bf2f(unsigned short s) {
  return __builtin_bit_cast(float, (unsigned)s << 16);
}

// LDS geometry (bf16 elements)
constexpr int QLN_ROW = 296;   // 4 h-blocks of 72 (d 49..63 zero-padded)
constexpr int QK_ROW  = 906;   // 4 h-blocks of 224 + 2 pad (row = 453 dwords, odd -> no 4-way LDS conflicts)

// Global panel geometry (fragment-native: slot = blk*512 + lane*8 + i)
constexpr int PK_ELEMS = 4 * 13 * 2 * 512;  // h, nt(c-tiles), ks(k=64)   = 53248
constexpr int PV_ELEMS = 4 * 4 * 7 * 512;   // h, nt(o-tiles), ks(k=224)  = 57344
constexpr size_t PANEL_BYTES = (size_t)(PK_ELEMS + PV_ELEMS) * sizeof(unsigned short);

// ======================= panel pack (runs once, tiny) =======================
__global__ void pack_panels(const float* __restrict__ Wk, const float* __restrict__ Wv,
                            unsigned short* __restrict__ pK, unsigned short* __restrict__ pV)
{
  int gid = blockIdx.x * 256 + threadIdx.x;
  if (gid < PK_ELEMS / 8) {
    int blk = gid >> 6;          // (h*13+nt)*2+ks
    int lane = gid & 63;
    int ks = blk & 1;
    int hnt = blk >> 1;
    int h = hnt / 13, nt = hnt % 13;
    int c = nt * 16 + (lane & 15);
    int d0 = ks * 32 + (lane >> 4) * 8;
    unsigned short v[8];
    #pragma unroll
    for (int i = 0; i < 8; ++i) {
      int d = d0 + i;
      float w = (d < 49 && c < 196) ? Wk[(size_t)(h * 49 + d) * 196 + c] : 0.f;
      v[i] = f2bf(w);
    }
    *reinterpret_cast<int4*>(&pK[(size_t)gid * 8]) = *reinterpret_cast<const int4*>(v);
  } else if (gid < PK_ELEMS / 8 + PV_ELEMS / 8) {
    int g2 = gid - PK_ELEMS / 8;
    int blk = g2 >> 6;           // (h*4+nt)*7+ks
    int lane = g2 & 63;
    int ks = blk % 7;
    int hnt = blk / 7;
    int h = hnt >> 2, nt = hnt & 3;
    int o = nt * 16 + (lane & 15);
    int c0 = ks * 32 + (lane >> 4) * 8;
    unsigned short v[8];
    #pragma unroll
    for (int i = 0; i < 8; ++i) {
      int c = c0 + i;
      float w = (o < 49 && c < 196) ? Wv[(size_t)(h * 49 + o) * 196 + c] : 0.f;
      v[i] = f2bf(w);
    }
    *reinterpret_cast<int4*>(&pV[(size_t)g2 * 8]) = *reinterpret_cast<const int4*>(v);
  }
}

// =============================== main kernel ================================
__global__ __launch_bounds__(256, 2)
void fused_main(const float* __restrict__ query, const float* __restrict__ context,
                const unsigned short* __restrict__ pK, const float* __restrict__ bk,
                const unsigned short* __restrict__ pV, const float* __restrict__ bv,
                const float* __restrict__ gamma, const float* __restrict__ beta,
                float* __restrict__ out, float* __restrict__ attn)
{
  __shared__ __align__(16) unsigned short qlnS[16 * QLN_ROW];  // 9472 B
  __shared__ __align__(16) unsigned short qkcb[16 * QK_ROW];   // 28992 B (qk, then cbar)
  __shared__ float sred[16 * 4 * 8];                           // 2048 B (scores -> probs)

  const int tid = threadIdx.x;
  const int pos0 = blockIdx.x * kTile;
  const int lane = tid & 63;
  const int wv = tid >> 6;      // wave 0..3
  const int l15 = lane & 15;
  const int g = lane >> 4;

  const float4* ctxF4 = reinterpret_cast<const float4*>(context);

  // ---------------- A: LayerNorm -> qln bf16 (h-blocked, d-padded) ------------
  {
    const int r = tid >> 4, s = tid & 15;
    const float4* q4 = reinterpret_cast<const float4*>(query) + (size_t)(pos0 + r) * 49;
    const float4* g4 = reinterpret_cast<const float4*>(gamma);
    const float4* b4 = reinterpret_cast<const float4*>(beta);
    float4 xv[4];
    float sum = 0.f, sumsq = 0.f;
    #pragma unroll
    for (int k = 0; k < 4; ++k) {
      int i4 = s + 16 * k;
      if (i4 < 49) {
        xv[k] = q4[i4];
        sum += xv[k].x + xv[k].y + xv[k].z + xv[k].w;
        sumsq += xv[k].x*xv[k].x + xv[k].y*xv[k].y + xv[k].z*xv[k].z + xv[k].w*xv[k].w;
      }
    }
    #pragma unroll
    for (int m = 1; m < 16; m <<= 1) {
      sum += __shfl_xor(sum, m, 16);
      sumsq += __shfl_xor(sumsq, m, 16);
    }
    const float mu = sum * (1.0f / 196.0f);
    const float var = sumsq * (1.0f / 196.0f) - mu * mu;
    const float rstd = rsqrtf(var + kEps);
    #pragma unroll
    for (int k = 0; k < 4; ++k) {
      int i4 = s + 16 * k;
      if (i4 < 49) {
        float4 gv = g4[i4], bt = b4[i4];
        float vo[4];
        vo[0] = (xv[k].x - mu) * rstd * gv.x + bt.x;
        vo[1] = (xv[k].y - mu) * rstd * gv.y + bt.y;
        vo[2] = (xv[k].z - mu) * rstd * gv.z + bt.z;
        vo[3] = (xv[k].w - mu) * rstd * gv.w + bt.w;
        #pragma unroll
        for (int j = 0; j < 4; ++j) {
          int oo = 4 * i4 + j;
          int hq = oo / 49, dq = oo - 49 * hq;
          qlnS[r * QLN_ROW + hq * 72 + dq] = f2bf(vo[j]);
        }
      }
    }
    #pragma unroll
    for (int it = 0; it < 6; ++it) {   // zero d-pad 49..71 per h-block
      int pp = s + 16 * it;
      if (pp < 92) {
        int hz = pp / 23, dz = 49 + pp - 23 * hz;
        qlnS[r * QLN_ROW + hz * 72 + dz] = 0;
      }
    }
  }
  __syncthreads();

  // ---------------- B: GEMM1 (wave wv = head wv; 13 c-tiles; one barrier) -----
  {
    const int h = wv;
    const bf16x8 a0 = *reinterpret_cast<const bf16x8*>(&qlnS[l15 * QLN_ROW + h * 72 + g * 8]);
    const bf16x8 a1 = *reinterpret_cast<const bf16x8*>(&qlnS[l15 * QLN_ROW + h * 72 + 32 + g * 8]);
    #pragma unroll 1
    for (int nt = 0; nt < 13; ++nt) {
      const unsigned short* pb = pK + ((size_t)(h * 13 + nt) * 2) * 512 + lane * 8;
      f32x4 acc = {0.f, 0.f, 0.f, 0.f};
      bf16x8 b0 = *reinterpret_cast<const bf16x8*>(pb);
      acc = __builtin_amdgcn_mfma_f32_16x16x32_bf16(a0, b0, acc, 0, 0, 0);
      bf16x8 b1 = *reinterpret_cast<const bf16x8*>(pb + 512);
      acc = __builtin_amdgcn_mfma_f32_16x16x32_bf16(a1, b1, acc, 0, 0, 0);
      #pragma unroll
      for (int r = 0; r < 4; ++r)      // D[row=g*4+r][col=nt*16+l15]
        qkcb[(g * 4 + r) * QK_ROW + h * 224 + nt * 16 + l15] = f2bf(acc[r]);
    }
  }
  __syncthreads();

  // ---------------- C: scores (ctx read #1) + softmax (round-3 structure) -----
  const int t = tid >> 4;
  const int x = tid & 15;
  for (int n = 0; n < 8; ++n) {
    float sph[4] = {0.f, 0.f, 0.f, 0.f};
    #pragma unroll
    for (int jj = 0; jj < 4; ++jj) {
      int c4 = x + 16 * jj;
      if (c4 < 49) {
        float4 cv = ctxF4[((size_t)(pos0 + t) * 8 + n) * 49 + c4];
        #pragma unroll
        for (int hh = 0; hh < 4; ++hh) {
          int2 q = *reinterpret_cast<const int2*>(&qkcb[t * QK_ROW + hh * 224 + 4 * c4]);
          float q0 = __builtin_bit_cast(float, (unsigned)q.x << 16);
          float q1 = __builtin_bit_cast(float, (unsigned)q.x & 0xffff0000u);
          float q2 = __builtin_bit_cast(float, (unsigned)q.y << 16);
          float q3 = __builtin_bit_cast(float, (unsigned)q.y & 0xffff0000u);
          sph[hh] += q0 * cv.x + q1 * cv.y + q2 * cv.z + q3 * cv.w;
        }
      }
    }
    #pragma unroll
    for (int hh = 0; hh < 4; ++hh) {
      #pragma unroll
      for (int m = 1; m < 16; m <<= 1) sph[hh] += __shfl_xor(sph[hh], m, 16);
    }
    if (x == 0) {
      #pragma unroll
      for (int hh = 0; hh < 4; ++hh) sred[(t * 4 + hh) * 8 + n] = sph[hh];
    }
  }
  __syncthreads();
  if (tid < 64) {
    const int tt = tid & 15, hh = tid >> 4;
    float qb = 0.f;
    for (int d = 0; d < 49; ++d)
      qb += bf2f(qlnS[tt * QLN_ROW + hh * 72 + d]) * bk[hh * 49 + d];
    const int pos = pos0 + tt;
    const int bb = pos >> 14, ll = pos & (kL - 1);
    float sc[8], m = -1e30f;
    #pragma unroll
    for (int n = 0; n < 8; ++n) {
      sc[n] = (sred[(tt * 4 + hh) * 8 + n] + qb) * kScale;
      m = fmaxf(m, sc[n]);
    }
    float ssum = 0.f;
    #pragma unroll
    for (int n = 0; n < 8; ++n) { sc[n] = __expf(sc[n] - m); ssum += sc[n]; }
    const float inv = 1.0f / ssum;
    float* ap = attn + (((size_t)bb * 4 + hh) * kL + ll) * 8;
    #pragma unroll
    for (int n = 0; n < 8; ++n) {
      float p = sc[n] * inv;
      sred[(tt * 4 + hh) * 8 + n] = p;   // scores -> probs in place
      ap[n] = p;
    }
  }
  __syncthreads();

  // ---------------- D: cbar (ctx read #2, L2-hot) -> bf16 (round-3 structure) --
  {
    float preg[4][8];
    #pragma unroll
    for (int hh = 0; hh < 4; ++hh)
      #pragma unroll
      for (int n = 0; n < 8; ++n) preg[hh][n] = sred[(t * 4 + hh) * 8 + n];
    #pragma unroll 1
    for (int jj = 0; jj < 4; ++jj) {
      int c4 = x + 16 * jj;
      if (c4 < 49) {
        float acc[4][4];
        #pragma unroll
        for (int hh = 0; hh < 4; ++hh)
          #pragma unroll
          for (int e = 0; e < 4; ++e) acc[hh][e] = 0.f;
        #pragma unroll
        for (int n = 0; n < 8; ++n) {
          float4 cv = ctxF4[((size_t)(pos0 + t) * 8 + n) * 49 + c4];
          #pragma unroll
          for (int hh = 0; hh < 4; ++hh) {
            float p = preg[hh][n];
            acc[hh][0] += p * cv.x; acc[hh][1] += p * cv.y;
            acc[hh][2] += p * cv.z; acc[hh][3] += p * cv.w;
          }
        }
        #pragma unroll
        for (int hh = 0; hh < 4; ++hh) {
          ushort4 pk4;
          pk4.x = f2bf(acc[hh][0]); pk4.y = f2bf(acc[hh][1]);
          pk4.z = f2bf(acc[hh][2]); pk4.w = f2bf(acc[hh][3]);
          *reinterpret_cast<ushort4*>(&qkcb[t * QK_ROW + hh * 224 + 4 * c4]) = pk4;
        }
      }
    }
    #pragma unroll
    for (int it = 0; it < 2; ++it) {   // zero c-pad 196..223
      int ii = tid + 256 * it;
      if (ii < 448) {
        int tz = ii / 28, rem = ii - 28 * tz;
        int hz = rem / 7, c4p = 49 + rem - 7 * hz;
        ushort4 z = {0, 0, 0, 0};
        *reinterpret_cast<ushort4*>(&qkcb[tz * QK_ROW + hz * 224 + 4 * c4p]) = z;
      }
    }
  }
  __syncthreads();

  // ---------------- E: GEMM2 (wave wv = head wv; 4 o-tiles) -------------------
  {
    const int h = wv;
    bf16x8 a[7];
    #pragma unroll
    for (int ks = 0; ks < 7; ++ks)
      a[ks] = *reinterpret_cast<const bf16x8*>(&qkcb[l15 * QK_ROW + h * 224 + ks * 32 + g * 8]);
    #pragma unroll 1
    for (int nt = 0; nt < 4; ++nt) {
      const unsigned short* pb = pV + ((size_t)(h * 4 + nt) * 7) * 512 + lane * 8;
      f32x4 acc = {0.f, 0.f, 0.f, 0.f};
      #pragma unroll
      for (int ks = 0; ks < 7; ++ks) {
        bf16x8 b = *reinterpret_cast<const bf16x8*>(pb + (size_t)ks * 512);
        acc = __builtin_amdgcn_mfma_f32_16x16x32_bf16(a[ks], b, acc, 0, 0, 0);
      }
      int o = nt * 16 + l15;
      if (o < 49) {
        float bvv = bv[h * 49 + o];
        #pragma unroll
        for (int r = 0; r < 4; ++r)
          out[(size_t)(pos0 + g * 4 + r) * 196 + h * 49 + o] = acc[r] + bvv;
      }
    }
  }
}

// ===================== fallback (round-3 kernel, ws-free) =====================
constexpr int PNL_ELEMS = 14336;

__global__ __launch_bounds__(256, 2)
void fused_triplane_v3(const float* __restrict__ query,
                    const float* __restrict__ context,
                    const float* __restrict__ Wk, const float* __restrict__ bk,
                    const float* __restrict__ Wv, const float* __restrict__ bv,
                    const float* __restrict__ gamma, const float* __restrict__ beta,
                    float* __restrict__ out, float* __restrict__ attn)
{
  __shared__ __align__(16) unsigned short pnl[PNL_ELEMS];
  __shared__ __align__(16) unsigned short qlnS[16 * QLN_ROW];
  __shared__ __align__(16) unsigned short qkcb[16 * QK_ROW];
  __shared__ float sred[16 * 4 * 8];

  const int tid = threadIdx.x;
  const int pos0 = blockIdx.x * kTile;
  const int lane = tid & 63;
  const int wv = tid >> 6;
  const int l15 = lane & 15;
  const int g = lane >> 4;

  const float4* WkF4 = reinterpret_cast<const float4*>(Wk);
  const float4* WvF4 = reinterpret_cast<const float4*>(Wv);
  const float4* ctxF4 = reinterpret_cast<const float4*>(context);

  {
    const int r = tid >> 4, s = tid & 15;
    const float4* q4 = reinterpret_cast<const float4*>(query) + (size_t)(pos0 + r) * 49;
    const float4* g4 = reinterpret_cast<const float4*>(gamma);
    const float4* b4 = reinterpret_cast<const float4*>(beta);
    float4 xv[4];
    float sum = 0.f, sumsq = 0.f;
    #pragma unroll
    for (int k = 0; k < 4; ++k) {
      int i4 = s + 16 * k;
      if (i4 < 49) {
        xv[k] = q4[i4];
        sum += xv[k].x + xv[k].y + xv[k].z + xv[k].w;
        sumsq += xv[k].x*xv[k].x + xv[k].y*xv[k].y + xv[k].z*xv[k].z + xv[k].w*xv[k].w;
      }
    }
    #pragma unroll
    for (int m = 1; m < 16; m <<= 1) {
      sum += __shfl_xor(sum, m, 16);
      sumsq += __shfl_xor(sumsq, m, 16);
    }
    const float mu = sum * (1.0f / 196.0f);
    const float var = sumsq * (1.0f / 196.0f) - mu * mu;
    const float rstd = rsqrtf(var + kEps);
    #pragma unroll
    for (int k = 0; k < 4; ++k) {
      int i4 = s + 16 * k;
      if (i4 < 49) {
        float4 gv = g4[i4], bt = b4[i4];
        float vo[4];
        vo[0] = (xv[k].x - mu) * rstd * gv.x + bt.x;
        vo[1] = (xv[k].y - mu) * rstd * gv.y + bt.y;
        vo[2] = (xv[k].z - mu) * rstd * gv.z + bt.z;
        vo[3] = (xv[k].w - mu) * rstd * gv.w + bt.w;
        #pragma unroll
        for (int j = 0; j < 4; ++j) {
          int oo = 4 * i4 + j;
          int hq = oo / 49, dq = oo - 49 * hq;
          qlnS[r * QLN_ROW + hq * 72 + dq] = f2bf(vo[j]);
        }
      }
    }
    #pragma unroll
    for (int it = 0; it < 6; ++it) {
      int pp = s + 16 * it;
      if (pp < 92) {
        int hz = pp / 23, dz = 49 + pp - 23 * hz;
        qlnS[r * QLN_ROW + hz * 72 + dz] = 0;
      }
    }
    #pragma unroll
    for (int k = 0; k < 7; ++k) {
      int idx8 = tid + 256 * k;
      *reinterpret_cast<int4*>(&pnl[idx8 * 8]) = make_int4(0, 0, 0, 0);
    }
  }
  __syncthreads();

  for (int h = 0; h < 4; ++h) {
    for (int it = 0; it < 10; ++it) {
      int idx = tid + 256 * it;
      if (idx < 2401) {
        int d = idx / 49, c4 = idx - 49 * d;
        float4 w = WkF4[(size_t)(h * 49 + d) * 49 + c4];
        int ks = d >> 5, gg = (d & 31) >> 3, ii = d & 7;
        float wa[4] = {w.x, w.y, w.z, w.w};
        #pragma unroll
        for (int j = 0; j < 4; ++j) {
          int cc = 4 * c4 + j;
          int nt = cc >> 4, lc = cc & 15;
          pnl[((nt << 1) | ks) * 512 + (gg * 16 + lc) * 8 + ii] = f2bf(wa[j]);
        }
      }
    }
    __syncthreads();
    {
      const bf16x8 a0 = *reinterpret_cast<const bf16x8*>(&qlnS[l15 * QLN_ROW + h * 72 + g * 8]);
      const bf16x8 a1 = *reinterpret_cast<const bf16x8*>(&qlnS[l15 * QLN_ROW + h * 72 + 32 + g * 8]);
      for (int nt = wv; nt < 13; nt += 4) {
        f32x4 acc = {0.f, 0.f, 0.f, 0.f};
        bf16x8 b0 = *reinterpret_cast<const bf16x8*>(&pnl[(nt * 2 + 0) * 512 + lane * 8]);
        acc = __builtin_amdgcn_mfma_f32_16x16x32_bf16(a0, b0, acc, 0, 0, 0);
        bf16x8 b1 = *reinterpret_cast<const bf16x8*>(&pnl[(nt * 2 + 1) * 512 + lane * 8]);
        acc = __builtin_amdgcn_mfma_f32_16x16x32_bf16(a1, b1, acc, 0, 0, 0);
        #pragma unroll
        for (int r = 0; r < 4; ++r)
          qkcb[(g * 4 + r) * QK_ROW + h * 224 + nt * 16 + l15] = f2bf(acc[r]);
      }
    }
    __syncthreads();
  }

  const int t = tid >> 4;
  const int x = tid & 15;
  for (int n = 0; n < 8; ++n) {
    float sph[4] = {0.f, 0.f, 0.f, 0.f};
    #pragma unroll
    for (int jj = 0; jj < 4; ++jj) {
      int c4 = x + 16 * jj;
      if (c4 < 49) {
        float4 cv = ctxF4[((size_t)(pos0 + t) * 8 + n) * 49 + c4];
        #pragma unroll
        for (int hh = 0; hh < 4; ++hh) {
          int2 q = *reinterpret_cast<const int2*>(&qkcb[t * QK_ROW + hh * 224 + 4 * c4]);
          float q0 = __builtin_bit_cast(float, (unsigned)q.x << 16);
          float q1 = __builtin_bit_cast(float, (unsigned)q.x & 0xffff0000u);
          float q2 = __builtin_bit_cast(float, (unsigned)q.y << 16);
          float q3 = __builtin_bit_cast(float, (unsigned)q.y & 0xffff0000u);
          sph[hh] += q0 * cv.x + q1 * cv.y + q2 * cv.z + q3 * cv.w;
        }
      }
    }
    #pragma unroll
    for (int hh = 0; hh < 4; ++hh) {
      #pragma unroll
      for (int m = 1; m < 16; m <<= 1) sph[hh] += __shfl_xor(sph[hh], m, 16);
    }
    if (x == 0) {
      #pragma unroll
      for (int hh = 0; hh < 4; ++hh) sred[(t * 4 + hh) * 8 + n] = sph[hh];
    }
  }
  __syncthreads();
  if (tid < 64) {
    const int tt = tid & 15, hh = tid >> 4;
    float qb = 0.f;
    for (int d = 0; d < 49; ++d)
      qb += bf2f(qlnS[tt * QLN_ROW + hh * 72 + d]) * bk[hh * 49 + d];
    const int pos = pos0 + tt;
    const int bb = pos >> 14, ll = pos & (kL - 1);
    float sc[8], m = -1e30f;
    #pragma unroll
    for (int n = 0; n < 8; ++n) {
      sc[n] = (sred[(tt * 4 + hh) * 8 + n] + qb) * kScale;
      m = fmaxf(m, sc[n]);
    }
    float ssum = 0.f;
    #pragma unroll
    for (int n = 0; n < 8; ++n) { sc[n] = __expf(sc[n] - m); ssum += sc[n]; }
    const float inv = 1.0f / ssum;
    float* ap = attn + (((size_t)bb * 4 + hh) * kL + ll) * 8;
    #pragma unroll
    for (int n = 0; n < 8; ++n) {
      float p = sc[n] * inv;
      sred[(tt * 4 + hh) * 8 + n] = p;
      ap[n] = p;
    }
  }
  __syncthreads();

  {
    float preg[4][8];
    #pragma unroll
    for (int hh = 0; hh < 4; ++hh)
      #pragma unroll
      for (int n = 0; n < 8; ++n) preg[hh][n] = sred[(t * 4 + hh) * 8 + n];
    #pragma unroll 1
    for (int jj = 0; jj < 4; ++jj) {
      int c4 = x + 16 * jj;
      if (c4 < 49) {
        float acc[4][4];
        #pragma unroll
        for (int hh = 0; hh < 4; ++hh)
          #pragma unroll
          for (int e = 0; e < 4; ++e) acc[hh][e] = 0.f;
        #pragma unroll
        for (int n = 0; n < 8; ++n) {
          float4 cv = ctxF4[((size_t)(pos0 + t) * 8 + n) * 49 + c4];
          #pragma unroll
          for (int hh = 0; hh < 4; ++hh) {
            float p = preg[hh][n];
            acc[hh][0] += p * cv.x; acc[hh][1] += p * cv.y;
            acc[hh][2] += p * cv.z; acc[hh][3] += p * cv.w;
          }
        }
        #pragma unroll
        for (int hh = 0; hh < 4; ++hh) {
          ushort4 pk4;
          pk4.x = f2bf(acc[hh][0]); pk4.y = f2bf(acc[hh][1]);
          pk4.z = f2bf(acc[hh][2]); pk4.w = f2bf(acc[hh][3]);
          *reinterpret_cast<ushort4*>(&qkcb[t * QK_ROW + hh * 224 + 4 * c4]) = pk4;
        }
      }
    }
    #pragma unroll
    for (int it = 0; it < 2; ++it) {
      int ii = tid + 256 * it;
      if (ii < 448) {
        int tz = ii / 28, rem = ii - 28 * tz;
        int hz = rem / 7, c4p = 49 + rem - 7 * hz;
        ushort4 z = {0, 0, 0, 0};
        *reinterpret_cast<ushort4*>(&qkcb[tz * QK_ROW + hz * 224 + 4 * c4p]) = z;
      }
    }
    #pragma unroll
    for (int k = 0; k < 7; ++k) {
      int idx8 = tid + 256 * k;
      *reinterpret_cast<int4*>(&pnl[idx8 * 8]) = make_int4(0, 0, 0, 0);
    }
  }
  __syncthreads();

  for (int h = 0; h < 4; ++h) {
    for (int it = 0; it < 10; ++it) {
      int idx = tid + 256 * it;
      if (idx < 2401) {
        int o = idx / 49, c4 = idx - 49 * o;
        float4 w = WvF4[(size_t)(h * 49 + o) * 49 + c4];
        int c0 = 4 * c4;
        int nt = o >> 4, lo = o & 15;
        int ks = c0 >> 5, gg = (c0 & 31) >> 3, i0 = c0 & 7;
        ushort4 pk4;
        pk4.x = f2bf(w.x); pk4.y = f2bf(w.y); pk4.z = f2bf(w.z); pk4.w = f2bf(w.w);
        *reinterpret_cast<ushort4*>(&pnl[(nt * 7 + ks) * 512 + (gg * 16 + lo) * 8 + i0]) = pk4;
      }
    }
    __syncthreads();
    {
      f32x4 acc = {0.f, 0.f, 0.f, 0.f};
      #pragma unroll
      for (int ks = 0; ks < 7; ++ks) {
        bf16x8 a = *reinterpret_cast<const bf16x8*>(&qkcb[l15 * QK_ROW + h * 224 + ks * 32 + g * 8]);
        bf16x8 b = *reinterpret_cast<const bf16x8*>(&pnl[(wv * 7 + ks) * 512 + lane * 8]);
        acc = __builtin_amdgcn_mfma_f32_16x16x32_bf16(a, b, acc, 0, 0, 0);
      }
      int o = wv * 16 + l15;
      if (o < 49) {
        float bvv = bv[h * 49 + o];
        #pragma unroll
        for (int r = 0; r < 4; ++r) {
          int tt2 = g * 4 + r;
          out[(size_t)(pos0 + tt2) * 196 + h * 49 + o] = acc[r] + bvv;
        }
      }
    }
    __syncthreads();
  }
}
} // namespace

extern "C" void kernel_launch(void* const* d_in, const int* in_sizes, int n_in,
                              void* d_out, int out_size, void* d_ws, size_t ws_size,
                              hipStream_t stream) {
  const float* query   = (const float*)d_in[0];
  const float* context = (const float*)d_in[1];
  const float* Wk      = (const float*)d_in[2];
  const float* bk      = (const float*)d_in[3];
  const float* Wv      = (const float*)d_in[4];
  const float* bv      = (const float*)d_in[5];
  const float* gamma   = (const float*)d_in[6];
  const float* beta    = (const float*)d_in[7];
  float* outp = (float*)d_out;
  float* attn = outp + (size_t)2 * kL * 196;   // out [B,L,C] then attn [B,H,L,Nv]

  const int nwg = (2 * kL) / kTile;  // 2048
  if (ws_size >= PANEL_BYTES) {
    unsigned short* pK = (unsigned short*)d_ws;
    unsigned short* pV = pK + PK_ELEMS;
    const int packThreads = (PK_ELEMS + PV_ELEMS) / 8;           // 13824
    pack_panels<<<dim3((packThreads + 255) / 256), dim3(256), 0, stream>>>(Wk, Wv, pK, pV);
    fused_main<<<dim3(nwg), dim3(256), 0, stream>>>(
        query, context, pK, bk, pV, bv, gamma, beta, outp, attn);
  } else {
    fused_triplane_v3<<<dim3(nwg), dim3(256), 0, stream>>>(
        query, context, Wk, bk, Wv, bv, gamma, beta, outp, attn);
  }
}